// Round 5
// baseline (1782.722 us; speedup 1.0000x reference)
//
#include <hip/hip_runtime.h>
#include <hip/hip_bf16.h>
#include <math.h>

typedef unsigned short u16;
typedef unsigned int u32;
typedef __attribute__((ext_vector_type(8))) short short8;
typedef __attribute__((ext_vector_type(4))) float f32x4;

__device__ __forceinline__ u16 f2b(float f) {
  u32 u = __builtin_bit_cast(u32, f);
  u = (u + 0x7fffu + ((u >> 16) & 1u)) >> 16;   // RNE
  return (u16)u;
}
__device__ __forceinline__ float b2f(u16 s) {
  return __builtin_bit_cast(float, (u32)s << 16);
}

// async global->LDS, 16B per lane; LDS dest = wave-uniform base + lane*16
__device__ __forceinline__ void ld_g2l(const u16* g, u16* l) {
  __builtin_amdgcn_global_load_lds(
      (const __attribute__((address_space(1))) unsigned int*)g,
      (__attribute__((address_space(3))) unsigned int*)l, 16, 0, 0);
}

// ---------------------------------------------------------------------------
// Core 128x128 tile GEMM (256 threads, 4 waves of 64x64), BK=32, pitch-32 LDS.
// ---------------------------------------------------------------------------
__device__ __forceinline__ void gemm_core(
    const u16* __restrict__ A, const u16* __restrict__ B,
    int lda, int ldb, int Klen, int kb, int bm, int bn,
    u16* __restrict__ As, u16* __restrict__ Bs, f32x4 (&acc)[4][4])
{
  int tid = threadIdx.x;
  int w = tid >> 6, lane = tid & 63;
  int srow = (w << 4) + (lane >> 2);       // 0..63
  int scol = (lane & 3) << 3;              // element 0,8,16,24
  const u16* ga0 = A + (long)(bm * 128 + srow) * lda + kb + scol;
  const u16* ga1 = ga0 + (long)64 * lda;
  const u16* gb0 = B + (long)(bn * 128 + srow) * ldb + kb + scol;
  const u16* gb1 = gb0 + (long)64 * ldb;
  u16* la0 = As + (w << 9);  u16* la1 = la0 + 2048;
  u16* lb0 = Bs + (w << 9);  u16* lb1 = lb0 + 2048;

  int wm = (w >> 1) << 6, wn = (w & 1) << 6;
  int lane15 = lane & 15, quad = lane >> 4;
  const u16* ar = As + (wm + lane15) * 32 + quad * 8;
  const u16* br = Bs + (wn + lane15) * 32 + quad * 8;

#pragma unroll
  for (int i = 0; i < 4; i++)
#pragma unroll
    for (int j = 0; j < 4; j++) { f32x4 z = {0.f, 0.f, 0.f, 0.f}; acc[i][j] = z; }

  for (int k = 0; k < Klen; k += 32) {
    ld_g2l(ga0 + k, la0);
    ld_g2l(ga1 + k, la1);
    ld_g2l(gb0 + k, lb0);
    ld_g2l(gb1 + k, lb1);
    __syncthreads();
    short8 af[4], bfr[4];
#pragma unroll
    for (int mt = 0; mt < 4; mt++) af[mt] = *(const short8*)(ar + mt * 16 * 32);
#pragma unroll
    for (int nt = 0; nt < 4; nt++) bfr[nt] = *(const short8*)(br + nt * 16 * 32);
#pragma unroll
    for (int mt = 0; mt < 4; mt++)
#pragma unroll
      for (int nt = 0; nt < 4; nt++)
        acc[mt][nt] = __builtin_amdgcn_mfma_f32_16x16x32_bf16(af[mt], bfr[nt], acc[mt][nt], 0, 0, 0);
    __syncthreads();
  }
}

// ---------------------------------------------------------------------------
// EPI: 0 = store f32
//      1 = relu -> rope -> bf16   (encoder GEMM producing QR directly)
//      3 = atomicAdd f32 (split-K)
//      4 = relu(acc) * unrope(C in-place) -> bf16  (xy over QR buffer)
// tri=1: A is strictly-lower-triangular -> clamp K at (bm+1)*128
// ---------------------------------------------------------------------------
template<int EPI>
__global__ __launch_bounds__(256, 2) void gemm_bt(
    const u16* __restrict__ A, const u16* __restrict__ B, void* __restrict__ C,
    int K, int lda, int ldb, int ldc, int nsplits, long aB, long bB, long cB,
    int tri)
{
  __shared__ __align__(16) u16 As[128 * 32];
  __shared__ __align__(16) u16 Bs[128 * 32];
  int bn = blockIdx.x, bm = blockIdx.y;
  int batch = blockIdx.z / nsplits, sp = blockIdx.z % nsplits;
  int Klen = K / nsplits, kb = sp * Klen;
  if (tri) {
    int kend = (bm + 1) * 128;               // A cols >= kend are all zero
    if (kb >= kend) return;
    if (kb + Klen > kend) Klen = kend - kb;
  }

  f32x4 acc[4][4];
  gemm_core(A + (long)batch * aB, B + (long)batch * bB, lda, ldb, Klen, kb, bm, bn, As, Bs, acc);

  int lane = threadIdx.x & 63, w = threadIdx.x >> 6;
  int wm = (w >> 1) << 6, wn = (w & 1) << 6;
  int lane15 = lane & 15, quad = lane >> 4;

  if (EPI == 1 || EPI == 4) {
    // rope/unrope with hoisted transcendentals: per nt, 1 exp2 + 3 sincos,
    // then exact angle-addition rotations across the 16 t-values.
    u16* Cp = (u16*)C;
#pragma unroll
    for (int nt = 0; nt < 4; nt++) {
      int gn = bn * 128 + wn + nt * 16 + lane15;
      float f = exp2f((float)(-(gn & ~1)) * (1.0f / 512.0f)) * 0.15915494f;
      int t0 = bm * 128 + wm + quad * 4;
      float ph0 = (float)t0 * f; ph0 -= floorf(ph0);
      float s0, c0; __sincosf(ph0 * 6.2831853f, &s0, &c0);
      float s1, c1; __sincosf(f * 6.2831853f, &s1, &c1);
      float ph16 = 16.f * f; ph16 -= floorf(ph16);
      float s16, c16; __sincosf(ph16 * 6.2831853f, &s16, &c16);
      float cm = c0, sm = s0;
#pragma unroll
      for (int mt = 0; mt < 4; mt++) {
        float cr = cm, sr = sm;
#pragma unroll
        for (int r = 0; r < 4; r++) {
          int gm = bm * 128 + wm + mt * 16 + quad * 4 + r;
          float v = acc[mt][nt][r];
          long ci = (long)(blockIdx.z / nsplits) * cB + (long)gm * ldc + gn;
          if (EPI == 1) {
            float rv = fmaxf(v, 0.f);
            float ro = __shfl_xor(rv, 1);
            float out = (gn & 1) ? (rv * cr + ro * sr) : (rv * cr - ro * sr);
            Cp[ci] = f2b(out);
          } else {
            float qv = b2f(Cp[ci]);
            float qo = __shfl_xor(qv, 1);
            float xs = (gn & 1) ? (qv * cr - qo * sr) : (qv * cr + qo * sr);  // un-rope
            Cp[ci] = f2b(fmaxf(v, 0.f) * xs);
          }
          float cn = cr * c1 - sr * s1; sr = sr * c1 + cr * s1; cr = cn;
        }
        float cn2 = cm * c16 - sm * s16; sm = sm * c16 + cm * s16; cm = cn2;
      }
    }
  } else {
#pragma unroll
    for (int mt = 0; mt < 4; mt++)
#pragma unroll
      for (int nt = 0; nt < 4; nt++) {
        int gn = bn * 128 + wn + nt * 16 + lane15;
#pragma unroll
        for (int r = 0; r < 4; r++) {
          int gm = bm * 128 + wm + mt * 16 + quad * 4 + r;
          float v = acc[mt][nt][r];
          long ci = (long)batch * cB + (long)gm * ldc + gn;
          if (EPI == 0) ((float*)C)[ci] = v;
          else          atomicAdd(&((float*)C)[ci], v);
        }
      }
  }
}

// ---------------------------------------------------------------------------
// scores split-K: grid (ntri, HB, NSP). Packed lower-triangle tile id -> (bm,bn),
// y = head, z = K-split. Atomic f32 accumulation into SF[head][T][T].
// ---------------------------------------------------------------------------
__global__ __launch_bounds__(256, 2) void gemm_scores_sk(
    const u16* __restrict__ QR, float* __restrict__ SF, int T, int nsp)
{
  __shared__ __align__(16) u16 As[128 * 32];
  __shared__ __align__(16) u16 Bs[128 * 32];
  int t = blockIdx.x;
  int bm = (int)((sqrtf(8.0f * t + 1.0f) - 1.0f) * 0.5f);
  while ((bm + 1) * (bm + 2) / 2 <= t) bm++;
  while (bm * (bm + 1) / 2 > t) bm--;
  int bn = t - bm * (bm + 1) / 2;

  const u16* Q = QR + (long)blockIdx.y * (long)T * 8192;
  float* S = SF + (long)blockIdx.y * (long)T * T;
  int Klen = 8192 / nsp, kb = blockIdx.z * Klen;

  f32x4 acc[4][4];
  gemm_core(Q, Q, 8192, 8192, Klen, kb, bm, bn, As, Bs, acc);

  int lane = threadIdx.x & 63, w = threadIdx.x >> 6;
  int wm = (w >> 1) << 6, wn = (w & 1) << 6;
  int lane15 = lane & 15, quad = lane >> 4;
#pragma unroll
  for (int mt = 0; mt < 4; mt++)
#pragma unroll
    for (int nt = 0; nt < 4; nt++)
#pragma unroll
      for (int r = 0; r < 4; r++) {
        int gm = bm * 128 + wm + mt * 16 + quad * 4 + r;
        int gn = bn * 128 + wn + nt * 16 + lane15;
        atomicAdd(&S[(long)gm * T + gn], acc[mt][nt][r]);
      }
}

// mask (strict lower) + f32->bf16 over packed triangle tiles; grid (ntri, HB)
__global__ __launch_bounds__(256) void scores_cvt(
    const float* __restrict__ SF, u16* __restrict__ SB, int T)
{
  int t = blockIdx.x;
  int bm = (int)((sqrtf(8.0f * t + 1.0f) - 1.0f) * 0.5f);
  while ((bm + 1) * (bm + 2) / 2 <= t) bm++;
  while (bm * (bm + 1) / 2 > t) bm--;
  int bn = t - bm * (bm + 1) / 2;
  const float* S = SF + (long)blockIdx.y * (long)T * T;
  u16* B = SB + (long)blockIdx.y * (long)T * T;
  for (int i = threadIdx.x; i < 2048; i += 256) {
    int r = i >> 4, c8 = (i & 15) << 3;
    int gm = bm * 128 + r, gn0 = bn * 128 + c8;
    const float* src = S + (long)gm * T + gn0;
    u32 out[4];
#pragma unroll
    for (int p = 0; p < 4; p++) {
      float e0 = (gm > gn0 + 2 * p)     ? src[2 * p]     : 0.f;
      float e1 = (gm > gn0 + 2 * p + 1) ? src[2 * p + 1] : 0.f;
      out[p] = (u32)f2b(e0) | ((u32)f2b(e1) << 16);
    }
    *(uint4*)(B + (long)gm * T + gn0) = make_uint4(out[0], out[1], out[2], out[3]);
  }
}

// ---------------------------------------------------------------------------
__global__ __launch_bounds__(256) void trans_f32_bf16(
    const float* __restrict__ src, u16* __restrict__ dst, int R, int C)
{
  __shared__ float tile[32][33];
  long off = (long)blockIdx.z * R * C;
  const float* s = src + off;
  u16* d = dst + off;
  int lx = threadIdx.x & 31, ly = threadIdx.x >> 5;
  int c = blockIdx.x * 32 + lx;
#pragma unroll
  for (int p = 0; p < 32; p += 8)
    tile[ly + p][lx] = s[(long)(blockIdx.y * 32 + ly + p) * C + c];
  __syncthreads();
  int rr = blockIdx.y * 32 + lx;
#pragma unroll
  for (int p = 0; p < 32; p += 8)
    d[(long)(blockIdx.x * 32 + ly + p) * R + rr] = f2b(tile[lx][ly + p]);
}

__device__ __forceinline__ float block_sum(float v, float* red) {
#pragma unroll
  for (int o = 32; o > 0; o >>= 1) v += __shfl_down(v, o, 64);
  int lane = threadIdx.x & 63, wid = threadIdx.x >> 6;
  if (lane == 0) red[wid] = v;
  __syncthreads();
  float r = red[0] + red[1] + red[2] + red[3];
  __syncthreads();
  return r;
}

__global__ __launch_bounds__(256) void embed_ln(
    const int* __restrict__ idx, const float* __restrict__ embed,
    float* __restrict__ x, u16* __restrict__ xb, u16* __restrict__ xT, int T)
{
  __shared__ float red[4];
  int t = blockIdx.x, d = threadIdx.x;
  float v = embed[(long)idx[t] * 256 + d];
  float mu = block_sum(v, red) * (1.f / 256.f);
  float c = v - mu;
  float var = block_sum(c * c, red) * (1.f / 256.f);
  float o = c * rsqrtf(var + 1e-5f);
  x[(long)t * 256 + d] = o;
  xb[(long)t * 256 + d] = f2b(o);
  xT[(long)d * T + t] = f2b(o);
}

__global__ __launch_bounds__(256) void row_ln(
    const float* __restrict__ in, u16* __restrict__ out)
{
  __shared__ float red[4];
  long row = blockIdx.x;
  int d = threadIdx.x;
  float v = in[row * 256 + d];
  float mu = block_sum(v, red) * (1.f / 256.f);
  float c = v - mu;
  float var = block_sum(c * c, red) * (1.f / 256.f);
  out[row * 256 + d] = f2b(c * rsqrtf(var + 1e-5f));
}

__global__ __launch_bounds__(256) void resid_ln(
    const float* __restrict__ yMLP, float* __restrict__ x,
    u16* __restrict__ xb, u16* __restrict__ xT, int T)
{
  __shared__ float red[4];
  int t = blockIdx.x, d = threadIdx.x;
  float y = yMLP[(long)t * 256 + d];
  float mu1 = block_sum(y, red) * (1.f / 256.f);
  float c1 = y - mu1;
  float var1 = block_sum(c1 * c1, red) * (1.f / 256.f);
  float l1 = c1 * rsqrtf(var1 + 1e-5f);
  float v = x[(long)t * 256 + d] + l1;
  float mu2 = block_sum(v, red) * (1.f / 256.f);
  float c2 = v - mu2;
  float var2 = block_sum(c2 * c2, red) * (1.f / 256.f);
  float o = c2 * rsqrtf(var2 + 1e-5f);
  x[(long)t * 256 + d] = o;
  xb[(long)t * 256 + d] = f2b(o);
  xT[(long)d * T + t] = f2b(o);
}

// ---------------------------------------------------------------------------
extern "C" void kernel_launch(void* const* d_in, const int* in_sizes, int n_in,
                              void* d_out, int out_size, void* d_ws, size_t ws_size,
                              hipStream_t stream) {
  const int*   idx       = (const int*)d_in[0];
  const float* embed     = (const float*)d_in[1];
  const float* encoder   = (const float*)d_in[2];
  const float* encoder_v = (const float*)d_in[3];
  const float* decoder   = (const float*)d_in[4];
  const float* lm_head   = (const float*)d_in[5];
  const int T = in_sizes[0];                 // 2048
  const int D = 256, NH = 4, Nn = 8192, V = 256;
  const int TB = T / 128, ntri = TB * (TB + 1) / 2;   // 16 -> 136

  char* ws = (char*)d_ws;
  size_t off = 0;
  auto alloc = [&](size_t bytes) -> void* {
    void* p = ws + off; off += (bytes + 255) & ~(size_t)255; return p;
  };
  float* x_f32   = (float*)alloc((size_t)T * D * 4);
  float* yMLP    = (float*)alloc((size_t)T * D * 4);
  float* yKV_f32 = (float*)alloc((size_t)NH * T * D * 4);
  u16* x_b    = (u16*)alloc((size_t)T * D * 2);
  u16* xT     = (u16*)alloc((size_t)T * D * 2);
  u16* yKV_b  = (u16*)alloc((size_t)NH * T * D * 2);
  u16* lmT    = (u16*)alloc((size_t)D * V * 2);
  u16* encT   = (u16*)alloc((size_t)NH * Nn * D * 2);
  u16* encvT  = (u16*)alloc((size_t)NH * Nn * D * 2);
  u16* decT   = (u16*)alloc((size_t)D * NH * Nn * 2);
  // head-batch ladder incl. scoresF: HB=4 -> ~295MB, HB=2 -> ~180MB, HB=1 -> ~123MB
  size_t per_head = ((size_t)T * T * 4 + 256) + ((size_t)T * T * 2 + 256) +
                    ((size_t)T * Nn * 2 + 256);
  int HB = 4;
  while (HB > 1 && off + (size_t)HB * per_head > ws_size) HB >>= 1;
  float* scoresF = (float*)alloc((size_t)HB * T * T * 4);
  u16*   scoresB = (u16*)alloc((size_t)HB * T * T * 2);
  u16*   QRxy    = (u16*)alloc((size_t)HB * T * Nn * 2);
  if (off > ws_size) return;

  // one-time weight prep: transpose to K-major bf16
  trans_f32_bf16<<<dim3(Nn / 32, D / 32, NH), 256, 0, stream>>>(encoder, encT, D, Nn);
  trans_f32_bf16<<<dim3(Nn / 32, D / 32, NH), 256, 0, stream>>>(encoder_v, encvT, D, Nn);
  trans_f32_bf16<<<dim3(D / 32, (NH * Nn) / 32, 1), 256, 0, stream>>>(decoder, decT, NH * Nn, D);
  trans_f32_bf16<<<dim3(V / 32, D / 32, 1), 256, 0, stream>>>(lm_head, lmT, D, V);

  embed_ln<<<T, 256, 0, stream>>>(idx, embed, x_f32, x_b, xT, T);

  for (int l = 0; l < 2; l++) {
    hipMemsetAsync(yMLP, 0, (size_t)T * D * 4, stream);
    for (int h0 = 0; h0 < NH; h0 += HB) {
      // QR = rope(relu(x @ encoder[h]))  (rope fused, hoisted transcendentals)
      gemm_bt<1><<<dim3(Nn / 128, T / 128, HB), 256, 0, stream>>>(
          x_b, encT + (size_t)h0 * Nn * D, QRxy,
          D, D, D, Nn, 1, 0L, (long)Nn * D, (long)T * Nn, 0);
      // scoresF = QR QR^T over lower-triangle tiles, split-K=4, atomic f32
      hipMemsetAsync(scoresF, 0, (size_t)HB * T * T * 4, stream);
      gemm_scores_sk<<<dim3(ntri, HB, 4), 256, 0, stream>>>(QRxy, scoresF, T, 4);
      // scoresB = tril(scoresF, -1) -> bf16 (upper tiles never read)
      scores_cvt<<<dim3(ntri, HB), 256, 0, stream>>>(scoresF, scoresB, T);
      // yKV = scores @ x (split-K=8, atomic f32, triangular K-clamp)
      hipMemsetAsync(yKV_f32, 0, (size_t)HB * T * D * 4, stream);
      gemm_bt<3><<<dim3(D / 128, T / 128, HB * 8), 256, 0, stream>>>(
          scoresB, xT, yKV_f32,
          T, T, T, D, 8, (long)T * T, 0L, (long)T * D, 1);
      // yKV = ln(yKV)
      row_ln<<<HB * T, 256, 0, stream>>>(yKV_f32, yKV_b);
      // xy = relu(yKV @ encoder_v[h]) * unrope(QR), in-place over QR
      gemm_bt<4><<<dim3(Nn / 128, T / 128, HB), 256, 0, stream>>>(
          yKV_b, encvT + (size_t)h0 * Nn * D, QRxy,
          D, D, D, Nn, 1, (long)T * D, (long)Nn * D, (long)T * Nn, 0);
      // yMLP += xy @ decoder[h]  (split-K=16, atomic f32)
      gemm_bt<3><<<dim3(D / 128, T / 128, HB * 16), 256, 0, stream>>>(
          QRxy, decT + (size_t)h0 * Nn, yMLP,
          Nn, Nn, NH * Nn, D, 16, (long)T * Nn, (long)Nn, 0L, 0);
    }
    resid_ln<<<T, 256, 0, stream>>>(yMLP, x_f32, x_b, xT, T);
  }

  // logits = x @ lm_head (f32 out)
  gemm_bt<0><<<dim3(V / 128, T / 128, 1), 256, 0, stream>>>(
      x_b, lmT, d_out, D, D, D, V, 1, 0L, 0L, 0L, 0);
}

// Round 6
// 1429.996 us; speedup vs baseline: 1.2467x; 1.2467x over previous
//
#include <hip/hip_runtime.h>
#include <hip/hip_bf16.h>
#include <math.h>

typedef unsigned short u16;
typedef unsigned int u32;
typedef __attribute__((ext_vector_type(8))) short short8;
typedef __attribute__((ext_vector_type(4))) float f32x4;

__device__ __forceinline__ u16 f2b(float f) {
  u32 u = __builtin_bit_cast(u32, f);
  u = (u + 0x7fffu + ((u >> 16) & 1u)) >> 16;   // RNE
  return (u16)u;
}
__device__ __forceinline__ float b2f(u16 s) {
  return __builtin_bit_cast(float, (u32)s << 16);
}

// async global->LDS, 16B per lane; LDS dest = wave-uniform base + lane*16
__device__ __forceinline__ void ld_g2l(const u16* g, u16* l) {
  __builtin_amdgcn_global_load_lds(
      (const __attribute__((address_space(1))) unsigned int*)g,
      (__attribute__((address_space(3))) unsigned int*)l, 16, 0, 0);
}

// s_waitcnt immediates (gfx9 encoding: vm[3:0], exp[6:4], lgkm[11:8], vm_hi[15:14])
#define WAITCNT_VM4 0x0F74   // vmcnt(4), lgkm/exp no-wait
#define WAITCNT_VM0 0x0F70   // vmcnt(0), lgkm/exp no-wait

// ---------------------------------------------------------------------------
// Double-buffered 128x128 tile GEMM core (256 thr, 4 waves of 64x64), BK=32.
// As/Bs each hold TWO 8KB buffers (offset 0 / 4096 elems). K-loop never
// drains vmcnt(0): next step's global_load_lds overlaps current MFMA.
// Safety: ds_reads are fenced by raw barriers; frag reads are lgkm-complete
// before barrier #2 because each feeds an MFMA issued before it.
// ---------------------------------------------------------------------------
__device__ __forceinline__ void gemm_core_db(
    const u16* __restrict__ A, const u16* __restrict__ B,
    int lda, int ldb, int Klen, int kb, int bm, int bn,
    u16* __restrict__ As, u16* __restrict__ Bs, f32x4 (&acc)[4][4])
{
  int tid = threadIdx.x;
  int w = tid >> 6, lane = tid & 63;
  int srow = (w << 4) + (lane >> 2);       // 0..63
  int scol = (lane & 3) << 3;              // element 0,8,16,24
  const u16* ga0 = A + (long)(bm * 128 + srow) * lda + kb + scol;
  const u16* ga1 = ga0 + (long)64 * lda;
  const u16* gb0 = B + (long)(bn * 128 + srow) * ldb + kb + scol;
  const u16* gb1 = gb0 + (long)64 * ldb;
  u16* la0 = As + (w << 9);
  u16* lb0 = Bs + (w << 9);

  int wm = (w >> 1) << 6, wn = (w & 1) << 6;
  int lane15 = lane & 15, quad = lane >> 4;
  const u16* ar = As + (wm + lane15) * 32 + quad * 8;
  const u16* br = Bs + (wn + lane15) * 32 + quad * 8;

#pragma unroll
  for (int i = 0; i < 4; i++)
#pragma unroll
    for (int j = 0; j < 4; j++) { f32x4 z = {0.f, 0.f, 0.f, 0.f}; acc[i][j] = z; }

  // prologue: stage buffer 0
  ld_g2l(ga0, la0);        ld_g2l(ga1, la0 + 2048);
  ld_g2l(gb0, lb0);        ld_g2l(gb1, lb0 + 2048);

  int p = 0;
  for (int k = 0; k < Klen; k += 32) {
    int koff = p ? 4096 : 0;
    int noff = p ? 0 : 4096;
    if (k + 32 < Klen) {                  // issue next step into other buffer
      ld_g2l(ga0 + k + 32, la0 + noff);
      ld_g2l(ga1 + k + 32, la0 + 2048 + noff);
      ld_g2l(gb0 + k + 32, lb0 + noff);
      ld_g2l(gb1 + k + 32, lb0 + 2048 + noff);
      __builtin_amdgcn_s_waitcnt(WAITCNT_VM4);   // own 4 oldest (cur buf) done
    } else {
      __builtin_amdgcn_s_waitcnt(WAITCNT_VM0);
    }
    __builtin_amdgcn_s_barrier();         // cur buffer staged by all waves

    short8 af[4], bfr[4];
#pragma unroll
    for (int mt = 0; mt < 4; mt++) af[mt] = *(const short8*)(ar + koff + mt * 512);
#pragma unroll
    for (int nt = 0; nt < 4; nt++) bfr[nt] = *(const short8*)(br + koff + nt * 512);
#pragma unroll
    for (int mt = 0; mt < 4; mt++)
#pragma unroll
      for (int nt = 0; nt < 4; nt++)
        acc[mt][nt] = __builtin_amdgcn_mfma_f32_16x16x32_bf16(af[mt], bfr[nt], acc[mt][nt], 0, 0, 0);

    __builtin_amdgcn_s_barrier();         // all waves consumed cur buffer
    p ^= 1;
  }
}

// ---------------------------------------------------------------------------
// EPI: 0 = store f32
//      1 = relu -> rope -> bf16   (encoder GEMM producing QR directly)
//      3 = atomicAdd f32 (split-K)
//      4 = relu(acc) * unrope(C in-place) -> bf16  (xy over QR buffer)
// tri=1: A is strictly-lower-triangular -> clamp K at (bm+1)*128
// ---------------------------------------------------------------------------
template<int EPI>
__global__ __launch_bounds__(256, 2) void gemm_bt(
    const u16* __restrict__ A, const u16* __restrict__ B, void* __restrict__ C,
    int K, int lda, int ldb, int ldc, int nsplits, long aB, long bB, long cB,
    int tri)
{
  __shared__ __align__(16) u16 As[2 * 128 * 32];
  __shared__ __align__(16) u16 Bs[2 * 128 * 32];
  int bn = blockIdx.x, bm = blockIdx.y;
  int batch = blockIdx.z / nsplits, sp = blockIdx.z % nsplits;
  int Klen = K / nsplits, kb = sp * Klen;
  if (tri) {
    int kend = (bm + 1) * 128;               // A cols >= kend are all zero
    if (kb >= kend) return;
    if (kb + Klen > kend) Klen = kend - kb;
  }

  f32x4 acc[4][4];
  gemm_core_db(A + (long)batch * aB, B + (long)batch * bB, lda, ldb, Klen, kb, bm, bn, As, Bs, acc);

  int lane = threadIdx.x & 63, w = threadIdx.x >> 6;
  int wm = (w >> 1) << 6, wn = (w & 1) << 6;
  int lane15 = lane & 15, quad = lane >> 4;

  if (EPI == 1 || EPI == 4) {
    // rope/unrope with hoisted transcendentals: per nt, 1 exp2 + 3 sincos,
    // then exact angle-addition rotations across the 16 t-values.
    u16* Cp = (u16*)C;
#pragma unroll
    for (int nt = 0; nt < 4; nt++) {
      int gn = bn * 128 + wn + nt * 16 + lane15;
      float f = exp2f((float)(-(gn & ~1)) * (1.0f / 512.0f)) * 0.15915494f;
      int t0 = bm * 128 + wm + quad * 4;
      float ph0 = (float)t0 * f; ph0 -= floorf(ph0);
      float s0, c0; __sincosf(ph0 * 6.2831853f, &s0, &c0);
      float s1, c1; __sincosf(f * 6.2831853f, &s1, &c1);
      float ph16 = 16.f * f; ph16 -= floorf(ph16);
      float s16, c16; __sincosf(ph16 * 6.2831853f, &s16, &c16);
      float cm = c0, sm = s0;
#pragma unroll
      for (int mt = 0; mt < 4; mt++) {
        float cr = cm, sr = sm;
#pragma unroll
        for (int r = 0; r < 4; r++) {
          int gm = bm * 128 + wm + mt * 16 + quad * 4 + r;
          float v = acc[mt][nt][r];
          long ci = (long)batch * cB + (long)gm * ldc + gn;
          if (EPI == 1) {
            float rv = fmaxf(v, 0.f);
            float ro = __shfl_xor(rv, 1);
            float out = (gn & 1) ? (rv * cr + ro * sr) : (rv * cr - ro * sr);
            Cp[ci] = f2b(out);
          } else {
            float qv = b2f(Cp[ci]);
            float qo = __shfl_xor(qv, 1);
            float xs = (gn & 1) ? (qv * cr - qo * sr) : (qv * cr + qo * sr);  // un-rope
            Cp[ci] = f2b(fmaxf(v, 0.f) * xs);
          }
          float cn = cr * c1 - sr * s1; sr = sr * c1 + cr * s1; cr = cn;
        }
        float cn2 = cm * c16 - sm * s16; sm = sm * c16 + cm * s16; cm = cn2;
      }
    }
  } else {
#pragma unroll
    for (int mt = 0; mt < 4; mt++)
#pragma unroll
      for (int nt = 0; nt < 4; nt++) {
        int gn = bn * 128 + wn + nt * 16 + lane15;
#pragma unroll
        for (int r = 0; r < 4; r++) {
          int gm = bm * 128 + wm + mt * 16 + quad * 4 + r;
          float v = acc[mt][nt][r];
          long ci = (long)batch * cB + (long)gm * ldc + gn;
          if (EPI == 0) ((float*)C)[ci] = v;
          else          atomicAdd(&((float*)C)[ci], v);
        }
      }
  }
}

// ---------------------------------------------------------------------------
// scores = tril(QR QR^T, -1) -> bf16. Packed lower-triangle grid:
// blockIdx.x in [0,136) -> (bm,bn); blockIdx.y = head. Upper tiles are never
// written and never read (yKV K-clamp stops at the diagonal).
// ---------------------------------------------------------------------------
__global__ __launch_bounds__(256, 2) void gemm_scores(
    const u16* __restrict__ QR, u16* __restrict__ S, int T)
{
  __shared__ __align__(16) u16 As[2 * 128 * 32];
  __shared__ __align__(16) u16 Bs[2 * 128 * 32];
  int t = blockIdx.x;
  int bm = (int)((sqrtf(8.0f * t + 1.0f) - 1.0f) * 0.5f);
  while ((bm + 1) * (bm + 2) / 2 <= t) bm++;
  while (bm * (bm + 1) / 2 > t) bm--;
  int bn = t - bm * (bm + 1) / 2;

  const u16* Q = QR + (long)blockIdx.y * (long)T * 8192;
  u16* Sb = S + (long)blockIdx.y * (long)T * T;

  f32x4 acc[4][4];
  gemm_core_db(Q, Q, 8192, 8192, 8192, 0, bm, bn, As, Bs, acc);

  int lane = threadIdx.x & 63, w = threadIdx.x >> 6;
  int wm = (w >> 1) << 6, wn = (w & 1) << 6;
  int lane15 = lane & 15, quad = lane >> 4;
#pragma unroll
  for (int mt = 0; mt < 4; mt++)
#pragma unroll
    for (int nt = 0; nt < 4; nt++)
#pragma unroll
      for (int r = 0; r < 4; r++) {
        int gm = bm * 128 + wm + mt * 16 + quad * 4 + r;
        int gn = bn * 128 + wn + nt * 16 + lane15;
        Sb[(long)gm * T + gn] = f2b(gm > gn ? acc[mt][nt][r] : 0.f);
      }
}

// ---------------------------------------------------------------------------
__global__ __launch_bounds__(256) void trans_f32_bf16(
    const float* __restrict__ src, u16* __restrict__ dst, int R, int C)
{
  __shared__ float tile[32][33];
  long off = (long)blockIdx.z * R * C;
  const float* s = src + off;
  u16* d = dst + off;
  int lx = threadIdx.x & 31, ly = threadIdx.x >> 5;
  int c = blockIdx.x * 32 + lx;
#pragma unroll
  for (int p = 0; p < 32; p += 8)
    tile[ly + p][lx] = s[(long)(blockIdx.y * 32 + ly + p) * C + c];
  __syncthreads();
  int rr = blockIdx.y * 32 + lx;
#pragma unroll
  for (int p = 0; p < 32; p += 8)
    d[(long)(blockIdx.x * 32 + ly + p) * R + rr] = f2b(tile[lx][ly + p]);
}

__device__ __forceinline__ float block_sum(float v, float* red) {
#pragma unroll
  for (int o = 32; o > 0; o >>= 1) v += __shfl_down(v, o, 64);
  int lane = threadIdx.x & 63, wid = threadIdx.x >> 6;
  if (lane == 0) red[wid] = v;
  __syncthreads();
  float r = red[0] + red[1] + red[2] + red[3];
  __syncthreads();
  return r;
}

__global__ __launch_bounds__(256) void embed_ln(
    const int* __restrict__ idx, const float* __restrict__ embed,
    float* __restrict__ x, u16* __restrict__ xb, u16* __restrict__ xT, int T)
{
  __shared__ float red[4];
  int t = blockIdx.x, d = threadIdx.x;
  float v = embed[(long)idx[t] * 256 + d];
  float mu = block_sum(v, red) * (1.f / 256.f);
  float c = v - mu;
  float var = block_sum(c * c, red) * (1.f / 256.f);
  float o = c * rsqrtf(var + 1e-5f);
  x[(long)t * 256 + d] = o;
  xb[(long)t * 256 + d] = f2b(o);
  xT[(long)d * T + t] = f2b(o);
}

__global__ __launch_bounds__(256) void row_ln(
    const float* __restrict__ in, u16* __restrict__ out)
{
  __shared__ float red[4];
  long row = blockIdx.x;
  int d = threadIdx.x;
  float v = in[row * 256 + d];
  float mu = block_sum(v, red) * (1.f / 256.f);
  float c = v - mu;
  float var = block_sum(c * c, red) * (1.f / 256.f);
  out[row * 256 + d] = f2b(c * rsqrtf(var + 1e-5f));
}

__global__ __launch_bounds__(256) void resid_ln(
    const float* __restrict__ yMLP, float* __restrict__ x,
    u16* __restrict__ xb, u16* __restrict__ xT, int T)
{
  __shared__ float red[4];
  int t = blockIdx.x, d = threadIdx.x;
  float y = yMLP[(long)t * 256 + d];
  float mu1 = block_sum(y, red) * (1.f / 256.f);
  float c1 = y - mu1;
  float var1 = block_sum(c1 * c1, red) * (1.f / 256.f);
  float l1 = c1 * rsqrtf(var1 + 1e-5f);
  float v = x[(long)t * 256 + d] + l1;
  float mu2 = block_sum(v, red) * (1.f / 256.f);
  float c2 = v - mu2;
  float var2 = block_sum(c2 * c2, red) * (1.f / 256.f);
  float o = c2 * rsqrtf(var2 + 1e-5f);
  x[(long)t * 256 + d] = o;
  xb[(long)t * 256 + d] = f2b(o);
  xT[(long)d * T + t] = f2b(o);
}

// ---------------------------------------------------------------------------
extern "C" void kernel_launch(void* const* d_in, const int* in_sizes, int n_in,
                              void* d_out, int out_size, void* d_ws, size_t ws_size,
                              hipStream_t stream) {
  const int*   idx       = (const int*)d_in[0];
  const float* embed     = (const float*)d_in[1];
  const float* encoder   = (const float*)d_in[2];
  const float* encoder_v = (const float*)d_in[3];
  const float* decoder   = (const float*)d_in[4];
  const float* lm_head   = (const float*)d_in[5];
  const int T = in_sizes[0];                 // 2048
  const int D = 256, NH = 4, Nn = 8192, V = 256;
  const int TB = T / 128, ntri = TB * (TB + 1) / 2;   // 16 -> 136

  char* ws = (char*)d_ws;
  size_t off = 0;
  auto alloc = [&](size_t bytes) -> void* {
    void* p = ws + off; off += (bytes + 255) & ~(size_t)255; return p;
  };
  float* x_f32   = (float*)alloc((size_t)T * D * 4);
  float* yMLP    = (float*)alloc((size_t)T * D * 4);
  float* yKV_f32 = (float*)alloc((size_t)NH * T * D * 4);
  u16* x_b    = (u16*)alloc((size_t)T * D * 2);
  u16* xT     = (u16*)alloc((size_t)T * D * 2);
  u16* yKV_b  = (u16*)alloc((size_t)NH * T * D * 2);
  u16* lmT    = (u16*)alloc((size_t)D * V * 2);
  u16* encT   = (u16*)alloc((size_t)NH * Nn * D * 2);
  u16* encvT  = (u16*)alloc((size_t)NH * Nn * D * 2);
  u16* decT   = (u16*)alloc((size_t)D * NH * Nn * 2);
  // head-batch ladder: HB=4 -> ~224MB total, HB=2 -> ~144MB, HB=1 -> ~104MB
  size_t per_head = ((size_t)T * T * 2 + 256) + ((size_t)T * Nn * 2 + 256);
  int HB = 4;
  while (HB > 1 && off + (size_t)HB * per_head > ws_size) HB >>= 1;
  u16* scores = (u16*)alloc((size_t)HB * T * T * 2);
  u16* QRxy   = (u16*)alloc((size_t)HB * T * Nn * 2);
  if (off > ws_size) return;

  // one-time weight prep: transpose to K-major bf16
  trans_f32_bf16<<<dim3(Nn / 32, D / 32, NH), 256, 0, stream>>>(encoder, encT, D, Nn);
  trans_f32_bf16<<<dim3(Nn / 32, D / 32, NH), 256, 0, stream>>>(encoder_v, encvT, D, Nn);
  trans_f32_bf16<<<dim3(D / 32, (NH * Nn) / 32, 1), 256, 0, stream>>>(decoder, decT, NH * Nn, D);
  trans_f32_bf16<<<dim3(V / 32, D / 32, 1), 256, 0, stream>>>(lm_head, lmT, D, V);

  embed_ln<<<T, 256, 0, stream>>>(idx, embed, x_f32, x_b, xT, T);

  for (int l = 0; l < 2; l++) {
    hipMemsetAsync(yMLP, 0, (size_t)T * D * 4, stream);
    for (int h0 = 0; h0 < NH; h0 += HB) {
      // QR = rope(relu(x @ encoder[h]))  (rope fused, hoisted transcendentals)
      gemm_bt<1><<<dim3(Nn / 128, T / 128, HB), 256, 0, stream>>>(
          x_b, encT + (size_t)h0 * Nn * D, QRxy,
          D, D, D, Nn, 1, 0L, (long)Nn * D, (long)T * Nn, 0);
      // scores = tril(QR QR^T, -1), packed triangular grid
      gemm_scores<<<dim3(ntri, HB, 1), 256, 0, stream>>>(QRxy, scores, T);
      // yKV = scores @ x (split-K=8, atomic f32, triangular K-clamp)
      hipMemsetAsync(yKV_f32, 0, (size_t)HB * T * D * 4, stream);
      gemm_bt<3><<<dim3(D / 128, T / 128, HB * 8), 256, 0, stream>>>(
          scores, xT, yKV_f32,
          T, T, T, D, 8, (long)T * T, 0L, (long)T * D, 1);
      // yKV = ln(yKV)
      row_ln<<<HB * T, 256, 0, stream>>>(yKV_f32, yKV_b);
      // xy = relu(yKV @ encoder_v[h]) * unrope(QR), in-place over QR
      gemm_bt<4><<<dim3(Nn / 128, T / 128, HB), 256, 0, stream>>>(
          yKV_b, encvT + (size_t)h0 * Nn * D, QRxy,
          D, D, D, Nn, 1, (long)T * D, (long)Nn * D, (long)T * Nn, 0);
      // yMLP += xy @ decoder[h]  (split-K=8, atomic f32)
      gemm_bt<3><<<dim3(D / 128, T / 128, HB * 8), 256, 0, stream>>>(
          QRxy, decT + (size_t)h0 * Nn, yMLP,
          Nn, Nn, NH * Nn, D, 8, (long)T * Nn, (long)Nn, 0L, 0);
    }
    resid_ln<<<T, 256, 0, stream>>>(yMLP, x_f32, x_b, xT, T);
  }

  // logits = x @ lm_head (f32 out)
  gemm_bt<0><<<dim3(V / 128, T / 128, 1), 256, 0, stream>>>(
      x_b, lmT, d_out, D, D, D, V, 1, 0L, 0L, 0L, 0);
}

// Round 7
// 1313.688 us; speedup vs baseline: 1.3570x; 1.0885x over previous
//
#include <hip/hip_runtime.h>
#include <hip/hip_bf16.h>
#include <math.h>

typedef unsigned short u16;
typedef unsigned int u32;
typedef __attribute__((ext_vector_type(8))) short short8;
typedef __attribute__((ext_vector_type(4))) float f32x4;

__device__ __forceinline__ u16 f2b(float f) {
  u32 u = __builtin_bit_cast(u32, f);
  u = (u + 0x7fffu + ((u >> 16) & 1u)) >> 16;   // RNE
  return (u16)u;
}
__device__ __forceinline__ float b2f(u16 s) {
  return __builtin_bit_cast(float, (u32)s << 16);
}

// async global->LDS, 16B per lane; LDS dest = wave-uniform base + lane*16
__device__ __forceinline__ void ld_g2l(const u16* g, u16* l) {
  __builtin_amdgcn_global_load_lds(
      (const __attribute__((address_space(1))) unsigned int*)g,
      (__attribute__((address_space(3))) unsigned int*)l, 16, 0, 0);
}

// ---------------------------------------------------------------------------
// 128x128 tile GEMM core, BK=64 per __syncthreads window (amortizes the
// barrier vmcnt-drain over 32 MFMA instead of 16). Four 8KB LDS planes:
// A-cols[0:32), A-cols[32:64), B-cols[0:32), B-cols[32:64), each pitch-32
// (conflict-free wave-contiguous b128 reads; lane-order matches ld_g2l).
// 256 threads, 4 waves of 64x64. Klen must be a multiple of 64.
// ---------------------------------------------------------------------------
__device__ __forceinline__ void gemm_core64(
    const u16* __restrict__ A, const u16* __restrict__ B,
    int lda, int ldb, int Klen, int kb, int bm, int bn,
    u16* __restrict__ A0, u16* __restrict__ A1,
    u16* __restrict__ B0, u16* __restrict__ B1, f32x4 (&acc)[4][4])
{
  int tid = threadIdx.x;
  int w = tid >> 6, lane = tid & 63;
  int srow = (w << 4) + (lane >> 2);       // 0..63
  int scol = (lane & 3) << 3;              // element 0,8,16,24
  const u16* ga0 = A + (long)(bm * 128 + srow) * lda + kb + scol;
  const u16* ga1 = ga0 + (long)64 * lda;
  const u16* gb0 = B + (long)(bn * 128 + srow) * ldb + kb + scol;
  const u16* gb1 = gb0 + (long)64 * ldb;
  int lo = w << 9;                          // wave's row group * pitch

  int wm = (w >> 1) << 6, wn = (w & 1) << 6;
  int lane15 = lane & 15, quad = lane >> 4;
  int fro = (wm + lane15) * 32 + quad * 8;  // A frag offset
  int fco = (wn + lane15) * 32 + quad * 8;  // B frag offset

#pragma unroll
  for (int i = 0; i < 4; i++)
#pragma unroll
    for (int j = 0; j < 4; j++) { f32x4 z = {0.f, 0.f, 0.f, 0.f}; acc[i][j] = z; }

  for (int k = 0; k < Klen; k += 64) {
    ld_g2l(ga0 + k,      A0 + lo); ld_g2l(ga1 + k,      A0 + lo + 2048);
    ld_g2l(ga0 + k + 32, A1 + lo); ld_g2l(ga1 + k + 32, A1 + lo + 2048);
    ld_g2l(gb0 + k,      B0 + lo); ld_g2l(gb1 + k,      B0 + lo + 2048);
    ld_g2l(gb0 + k + 32, B1 + lo); ld_g2l(gb1 + k + 32, B1 + lo + 2048);
    __syncthreads();                        // drains vmcnt -> staging visible
#pragma unroll
    for (int kg = 0; kg < 2; kg++) {
      const u16* ar = (kg ? A1 : A0) + fro;
      const u16* br = (kg ? B1 : B0) + fco;
      short8 af[4], bfr[4];
#pragma unroll
      for (int mt = 0; mt < 4; mt++) af[mt] = *(const short8*)(ar + mt * 512);
#pragma unroll
      for (int nt = 0; nt < 4; nt++) bfr[nt] = *(const short8*)(br + nt * 512);
#pragma unroll
      for (int mt = 0; mt < 4; mt++)
#pragma unroll
        for (int nt = 0; nt < 4; nt++)
          acc[mt][nt] = __builtin_amdgcn_mfma_f32_16x16x32_bf16(af[mt], bfr[nt], acc[mt][nt], 0, 0, 0);
    }
    __syncthreads();                        // frags consumed; LDS reusable
  }
}

// ---------------------------------------------------------------------------
// EPI: 0 = store f32
//      1 = relu -> rope -> bf16   (encoder GEMM producing QR directly)
//      3 = atomicAdd f32 (split-K)
//      4 = relu(acc) * unrope(C in-place) -> bf16  (xy over QR buffer)
// tri=1: A is strictly-lower-triangular -> clamp K at (bm+1)*128
// ---------------------------------------------------------------------------
template<int EPI>
__global__ __launch_bounds__(256, 2) void gemm_bt(
    const u16* __restrict__ A, const u16* __restrict__ B, void* __restrict__ C,
    int K, int lda, int ldb, int ldc, int nsplits, long aB, long bB, long cB,
    int tri)
{
  __shared__ __align__(16) u16 A0[4096], A1[4096], B0[4096], B1[4096];
  int bn = blockIdx.x, bm = blockIdx.y;
  int batch = blockIdx.z / nsplits, sp = blockIdx.z % nsplits;
  int Klen = K / nsplits, kb = sp * Klen;
  if (tri) {
    int kend = (bm + 1) * 128;               // A cols >= kend are all zero
    if (kb >= kend) return;
    if (kb + Klen > kend) Klen = kend - kb;  // stays a multiple of 128
  }

  f32x4 acc[4][4];
  gemm_core64(A + (long)batch * aB, B + (long)batch * bB, lda, ldb, Klen, kb,
              bm, bn, A0, A1, B0, B1, acc);

  int lane = threadIdx.x & 63, w = threadIdx.x >> 6;
  int wm = (w >> 1) << 6, wn = (w & 1) << 6;
  int lane15 = lane & 15, quad = lane >> 4;

  if (EPI == 1 || EPI == 4) {
    // rope/unrope with hoisted transcendentals: per nt, 1 exp2 + 3 sincos,
    // then exact angle-addition rotations across the 16 t-values.
    u16* Cp = (u16*)C;
#pragma unroll
    for (int nt = 0; nt < 4; nt++) {
      int gn = bn * 128 + wn + nt * 16 + lane15;
      float f = exp2f((float)(-(gn & ~1)) * (1.0f / 512.0f)) * 0.15915494f;
      int t0 = bm * 128 + wm + quad * 4;
      float ph0 = (float)t0 * f; ph0 -= floorf(ph0);
      float s0, c0; __sincosf(ph0 * 6.2831853f, &s0, &c0);
      float s1, c1; __sincosf(f * 6.2831853f, &s1, &c1);
      float ph16 = 16.f * f; ph16 -= floorf(ph16);
      float s16, c16; __sincosf(ph16 * 6.2831853f, &s16, &c16);
      float cm = c0, sm = s0;
#pragma unroll
      for (int mt = 0; mt < 4; mt++) {
        float cr = cm, sr = sm;
#pragma unroll
        for (int r = 0; r < 4; r++) {
          int gm = bm * 128 + wm + mt * 16 + quad * 4 + r;
          float v = acc[mt][nt][r];
          long ci = (long)batch * cB + (long)gm * ldc + gn;
          if (EPI == 1) {
            float rv = fmaxf(v, 0.f);
            float ro = __shfl_xor(rv, 1);
            float out = (gn & 1) ? (rv * cr + ro * sr) : (rv * cr - ro * sr);
            Cp[ci] = f2b(out);
          } else {
            float qv = b2f(Cp[ci]);
            float qo = __shfl_xor(qv, 1);
            float xs = (gn & 1) ? (qv * cr - qo * sr) : (qv * cr + qo * sr);  // un-rope
            Cp[ci] = f2b(fmaxf(v, 0.f) * xs);
          }
          float cn = cr * c1 - sr * s1; sr = sr * c1 + cr * s1; cr = cn;
        }
        float cn2 = cm * c16 - sm * s16; sm = sm * c16 + cm * s16; cm = cn2;
      }
    }
  } else {
#pragma unroll
    for (int mt = 0; mt < 4; mt++)
#pragma unroll
      for (int nt = 0; nt < 4; nt++) {
        int gn = bn * 128 + wn + nt * 16 + lane15;
#pragma unroll
        for (int r = 0; r < 4; r++) {
          int gm = bm * 128 + wm + mt * 16 + quad * 4 + r;
          float v = acc[mt][nt][r];
          long ci = (long)batch * cB + (long)gm * ldc + gn;
          if (EPI == 0) ((float*)C)[ci] = v;
          else          atomicAdd(&((float*)C)[ci], v);
        }
      }
  }
}

// ---------------------------------------------------------------------------
// scores = tril(QR QR^T, -1) -> bf16. Packed lower-triangle grid:
// blockIdx.x in [0,136) -> (bm,bn); blockIdx.y = head. Upper tiles are never
// written and never read (yKV K-clamp stops at the diagonal).
// ---------------------------------------------------------------------------
__global__ __launch_bounds__(256, 2) void gemm_scores(
    const u16* __restrict__ QR, u16* __restrict__ S, int T)
{
  __shared__ __align__(16) u16 A0[4096], A1[4096], B0[4096], B1[4096];
  int t = blockIdx.x;
  int bm = (int)((sqrtf(8.0f * t + 1.0f) - 1.0f) * 0.5f);
  while ((bm + 1) * (bm + 2) / 2 <= t) bm++;
  while (bm * (bm + 1) / 2 > t) bm--;
  int bn = t - bm * (bm + 1) / 2;

  const u16* Q = QR + (long)blockIdx.y * (long)T * 8192;
  u16* Sb = S + (long)blockIdx.y * (long)T * T;

  f32x4 acc[4][4];
  gemm_core64(Q, Q, 8192, 8192, 8192, 0, bm, bn, A0, A1, B0, B1, acc);

  int lane = threadIdx.x & 63, w = threadIdx.x >> 6;
  int wm = (w >> 1) << 6, wn = (w & 1) << 6;
  int lane15 = lane & 15, quad = lane >> 4;
#pragma unroll
  for (int mt = 0; mt < 4; mt++)
#pragma unroll
    for (int nt = 0; nt < 4; nt++)
#pragma unroll
      for (int r = 0; r < 4; r++) {
        int gm = bm * 128 + wm + mt * 16 + quad * 4 + r;
        int gn = bn * 128 + wn + nt * 16 + lane15;
        Sb[(long)gm * T + gn] = f2b(gm > gn ? acc[mt][nt][r] : 0.f);
      }
}

// ---------------------------------------------------------------------------
__global__ __launch_bounds__(256) void trans_f32_bf16(
    const float* __restrict__ src, u16* __restrict__ dst, int R, int C)
{
  __shared__ float tile[32][33];
  long off = (long)blockIdx.z * R * C;
  const float* s = src + off;
  u16* d = dst + off;
  int lx = threadIdx.x & 31, ly = threadIdx.x >> 5;
  int c = blockIdx.x * 32 + lx;
#pragma unroll
  for (int p = 0; p < 32; p += 8)
    tile[ly + p][lx] = s[(long)(blockIdx.y * 32 + ly + p) * C + c];
  __syncthreads();
  int rr = blockIdx.y * 32 + lx;
#pragma unroll
  for (int p = 0; p < 32; p += 8)
    d[(long)(blockIdx.x * 32 + ly + p) * R + rr] = f2b(tile[lx][ly + p]);
}

__device__ __forceinline__ float block_sum(float v, float* red) {
#pragma unroll
  for (int o = 32; o > 0; o >>= 1) v += __shfl_down(v, o, 64);
  int lane = threadIdx.x & 63, wid = threadIdx.x >> 6;
  if (lane == 0) red[wid] = v;
  __syncthreads();
  float r = red[0] + red[1] + red[2] + red[3];
  __syncthreads();
  return r;
}

__global__ __launch_bounds__(256) void embed_ln(
    const int* __restrict__ idx, const float* __restrict__ embed,
    float* __restrict__ x, u16* __restrict__ xb, u16* __restrict__ xT, int T)
{
  __shared__ float red[4];
  int t = blockIdx.x, d = threadIdx.x;
  float v = embed[(long)idx[t] * 256 + d];
  float mu = block_sum(v, red) * (1.f / 256.f);
  float c = v - mu;
  float var = block_sum(c * c, red) * (1.f / 256.f);
  float o = c * rsqrtf(var + 1e-5f);
  x[(long)t * 256 + d] = o;
  xb[(long)t * 256 + d] = f2b(o);
  xT[(long)d * T + t] = f2b(o);
}

__global__ __launch_bounds__(256) void row_ln(
    const float* __restrict__ in, u16* __restrict__ out)
{
  __shared__ float red[4];
  long row = blockIdx.x;
  int d = threadIdx.x;
  float v = in[row * 256 + d];
  float mu = block_sum(v, red) * (1.f / 256.f);
  float c = v - mu;
  float var = block_sum(c * c, red) * (1.f / 256.f);
  out[row * 256 + d] = f2b(c * rsqrtf(var + 1e-5f));
}

__global__ __launch_bounds__(256) void resid_ln(
    const float* __restrict__ yMLP, float* __restrict__ x,
    u16* __restrict__ xb, u16* __restrict__ xT, int T)
{
  __shared__ float red[4];
  int t = blockIdx.x, d = threadIdx.x;
  float y = yMLP[(long)t * 256 + d];
  float mu1 = block_sum(y, red) * (1.f / 256.f);
  float c1 = y - mu1;
  float var1 = block_sum(c1 * c1, red) * (1.f / 256.f);
  float l1 = c1 * rsqrtf(var1 + 1e-5f);
  float v = x[(long)t * 256 + d] + l1;
  float mu2 = block_sum(v, red) * (1.f / 256.f);
  float c2 = v - mu2;
  float var2 = block_sum(c2 * c2, red) * (1.f / 256.f);
  float o = c2 * rsqrtf(var2 + 1e-5f);
  x[(long)t * 256 + d] = o;
  xb[(long)t * 256 + d] = f2b(o);
  xT[(long)d * T + t] = f2b(o);
}

// ---------------------------------------------------------------------------
extern "C" void kernel_launch(void* const* d_in, const int* in_sizes, int n_in,
                              void* d_out, int out_size, void* d_ws, size_t ws_size,
                              hipStream_t stream) {
  const int*   idx       = (const int*)d_in[0];
  const float* embed     = (const float*)d_in[1];
  const float* encoder   = (const float*)d_in[2];
  const float* encoder_v = (const float*)d_in[3];
  const float* decoder   = (const float*)d_in[4];
  const float* lm_head   = (const float*)d_in[5];
  const int T = in_sizes[0];                 // 2048
  const int D = 256, NH = 4, Nn = 8192, V = 256;
  const int TB = T / 128, ntri = TB * (TB + 1) / 2;   // 16 -> 136

  char* ws = (char*)d_ws;
  size_t off = 0;
  auto alloc = [&](size_t bytes) -> void* {
    void* p = ws + off; off += (bytes + 255) & ~(size_t)255; return p;
  };
  float* x_f32   = (float*)alloc((size_t)T * D * 4);
  float* yMLP    = (float*)alloc((size_t)T * D * 4);
  float* yKV_f32 = (float*)alloc((size_t)NH * T * D * 4);
  u16* x_b    = (u16*)alloc((size_t)T * D * 2);
  u16* xT     = (u16*)alloc((size_t)T * D * 2);
  u16* yKV_b  = (u16*)alloc((size_t)NH * T * D * 2);
  u16* lmT    = (u16*)alloc((size_t)D * V * 2);
  u16* encT   = (u16*)alloc((size_t)NH * Nn * D * 2);
  u16* encvT  = (u16*)alloc((size_t)NH * Nn * D * 2);
  u16* decT   = (u16*)alloc((size_t)D * NH * Nn * 2);
  // head-batch ladder: HB=4 -> ~224MB total, HB=2 -> ~144MB, HB=1 -> ~104MB
  size_t per_head = ((size_t)T * T * 2 + 256) + ((size_t)T * Nn * 2 + 256);
  int HB = 4;
  while (HB > 1 && off + (size_t)HB * per_head > ws_size) HB >>= 1;
  u16* scores = (u16*)alloc((size_t)HB * T * T * 2);
  u16* QRxy   = (u16*)alloc((size_t)HB * T * Nn * 2);
  if (off > ws_size) return;

  // one-time weight prep: transpose to K-major bf16
  trans_f32_bf16<<<dim3(Nn / 32, D / 32, NH), 256, 0, stream>>>(encoder, encT, D, Nn);
  trans_f32_bf16<<<dim3(Nn / 32, D / 32, NH), 256, 0, stream>>>(encoder_v, encvT, D, Nn);
  trans_f32_bf16<<<dim3(D / 32, (NH * Nn) / 32, 1), 256, 0, stream>>>(decoder, decT, NH * Nn, D);
  trans_f32_bf16<<<dim3(V / 32, D / 32, 1), 256, 0, stream>>>(lm_head, lmT, D, V);

  embed_ln<<<T, 256, 0, stream>>>(idx, embed, x_f32, x_b, xT, T);

  for (int l = 0; l < 2; l++) {
    hipMemsetAsync(yMLP, 0, (size_t)T * D * 4, stream);
    for (int h0 = 0; h0 < NH; h0 += HB) {
      // QR = rope(relu(x @ encoder[h]))  (rope fused, hoisted transcendentals)
      gemm_bt<1><<<dim3(Nn / 128, T / 128, HB), 256, 0, stream>>>(
          x_b, encT + (size_t)h0 * Nn * D, QRxy,
          D, D, D, Nn, 1, 0L, (long)Nn * D, (long)T * Nn, 0);
      // scores = tril(QR QR^T, -1), packed triangular grid
      gemm_scores<<<dim3(ntri, HB, 1), 256, 0, stream>>>(QRxy, scores, T);
      // yKV = scores @ x (split-K=8, atomic f32, triangular K-clamp)
      hipMemsetAsync(yKV_f32, 0, (size_t)HB * T * D * 4, stream);
      gemm_bt<3><<<dim3(D / 128, T / 128, HB * 8), 256, 0, stream>>>(
          scores, xT, yKV_f32,
          T, T, T, D, 8, (long)T * T, 0L, (long)T * D, 1);
      // yKV = ln(yKV)
      row_ln<<<HB * T, 256, 0, stream>>>(yKV_f32, yKV_b);
      // xy = relu(yKV @ encoder_v[h]) * unrope(QR), in-place over QR
      gemm_bt<4><<<dim3(Nn / 128, T / 128, HB), 256, 0, stream>>>(
          yKV_b, encvT + (size_t)h0 * Nn * D, QRxy,
          D, D, D, Nn, 1, (long)T * D, (long)Nn * D, (long)T * Nn, 0);
      // yMLP += xy @ decoder[h]  (split-K=8, atomic f32)
      gemm_bt<3><<<dim3(D / 128, T / 128, HB * 8), 256, 0, stream>>>(
          QRxy, decT + (size_t)h0 * Nn, yMLP,
          Nn, Nn, NH * Nn, D, 8, (long)T * Nn, (long)Nn, 0L, 0);
    }
    resid_ln<<<T, 256, 0, stream>>>(yMLP, x_f32, x_b, xT, T);
  }

  // logits = x @ lm_head (f32 out)
  gemm_bt<0><<<dim3(V / 128, T / 128, 1), 256, 0, stream>>>(
      x_b, lmT, d_out, D, D, D, V, 1, 0L, 0L, 0L, 0);
}